// Round 1
// baseline (1751.344 us; speedup 1.0000x reference)
//
#include <hip/hip_runtime.h>

#define N_ITEMS 20000
#define N_REC 8
#define N_USERS 2048
#define ITEMS_PER_BLOCK 80
#define NCHUNKS (N_ITEMS / ITEMS_PER_BLOCK)  // 250

// Pass 1: scores = sum_r input[i*8+r][u] * w[r]  -> d_out
//         per-user max -> d_ws (atomicMax on int bits; scores >= 0)
__global__ __launch_bounds__(256) void score_max_kernel(
    const float* __restrict__ inp, const float* __restrict__ w,
    float* __restrict__ out, float* __restrict__ maxbuf)
{
    const int u = (blockIdx.x * 256 + threadIdx.x) * 4;   // user start (0..2044)
    const int item0 = blockIdx.y * ITEMS_PER_BLOCK;

    float wr[N_REC];
#pragma unroll
    for (int r = 0; r < N_REC; ++r) wr[r] = w[r];

    // scores are >= 0 (inputs in [0,1), w >= 0); 0 is a safe identity vs memset(0)
    float4 mx = make_float4(0.f, 0.f, 0.f, 0.f);

    for (int i = item0; i < item0 + ITEMS_PER_BLOCK; ++i) {
        const float* base = inp + (size_t)i * N_REC * N_USERS + u;
        float4 acc = make_float4(0.f, 0.f, 0.f, 0.f);
#pragma unroll
        for (int r = 0; r < N_REC; ++r) {
            float4 v = *(const float4*)(base + (size_t)r * N_USERS);
            acc.x += v.x * wr[r];
            acc.y += v.y * wr[r];
            acc.z += v.z * wr[r];
            acc.w += v.w * wr[r];
        }
        *(float4*)(out + (size_t)i * N_USERS + u) = acc;
        mx.x = fmaxf(mx.x, acc.x);
        mx.y = fmaxf(mx.y, acc.y);
        mx.z = fmaxf(mx.z, acc.z);
        mx.w = fmaxf(mx.w, acc.w);
    }

    // positive floats compare identically as signed ints
    atomicMax((int*)(maxbuf + u + 0), __float_as_int(mx.x));
    atomicMax((int*)(maxbuf + u + 1), __float_as_int(mx.y));
    atomicMax((int*)(maxbuf + u + 2), __float_as_int(mx.z));
    atomicMax((int*)(maxbuf + u + 3), __float_as_int(mx.w));
}

// Pass 2: out[i][u] /= max[u], one float4 per thread
__global__ __launch_bounds__(256) void norm_kernel(
    float* __restrict__ out, const float* __restrict__ maxbuf)
{
    const size_t idx = (size_t)blockIdx.x * 256 + threadIdx.x; // float4 index
    const int uf4 = (int)(idx & (N_USERS / 4 - 1));            // row len = 512 float4
    float4 m = *(const float4*)(maxbuf + uf4 * 4);
    float4 v = *(const float4*)(out + idx * 4);
    v.x /= m.x;
    v.y /= m.y;
    v.z /= m.z;
    v.w /= m.w;
    *(float4*)(out + idx * 4) = v;
}

extern "C" void kernel_launch(void* const* d_in, const int* in_sizes, int n_in,
                              void* d_out, int out_size, void* d_ws, size_t ws_size,
                              hipStream_t stream) {
    const float* inp = (const float*)d_in[0];
    const float* w   = (const float*)d_in[1];
    float* out       = (float*)d_out;
    float* maxbuf    = (float*)d_ws;

    // ws is poisoned to 0xAA before every launch; zero the 2048-float max buffer
    hipMemsetAsync(maxbuf, 0, N_USERS * sizeof(float), stream);

    dim3 grid1(N_USERS / (256 * 4), NCHUNKS);  // (2, 250)
    score_max_kernel<<<grid1, 256, 0, stream>>>(inp, w, out, maxbuf);

    const int total_f4 = N_ITEMS * N_USERS / 4;          // 10,240,000
    norm_kernel<<<total_f4 / 256, 256, 0, stream>>>(out, maxbuf);
}